// Round 8
// baseline (26.195 us; speedup 1.0000x reference)
//
#include <hip/hip_runtime.h>
#include <hip/hip_bf16.h>
#include <math.h>

// max_{n,m} ||L[n]-R[m]||, L,R: [8192][64] fp32.
// R8: occupancy + no-LDS-in-loop. Wave tile 64m x 32n (acc 32 regs), A-frags
// in regs (loop-invariant), B-frags reg ping-pong (prefetch t+1), deferred-lsq
// slot-max so the 8-iter n-loop has ZERO LDS accesses and ZERO barriers.
// ~140 VGPR -> __launch_bounds__(256,3) -> 12 waves/CU (was 8).

typedef __attribute__((ext_vector_type(8)))  short  short8;   // bf16x8 frag
typedef __attribute__((ext_vector_type(4)))  float  f32x4;
typedef __attribute__((ext_vector_type(16))) float  f32x16;   // 32x32 accum

constexpr int D  = 64;
constexpr int NR = 8192;
constexpr int NSLOT = 1024;

__device__ __forceinline__ short f2bf(float f) {
    __hip_bfloat16 h = __float2bfloat16(f);
    return __builtin_bit_cast(short, h);
}

// Frag-packed layout: row r, k-chunk kk (16 k's), k-half kh, elem e:
//   short index = ((r>>5)*4 + kk)*512 + (kh*32 + (r&31))*8 + e
// -> a wave's frag access at [group][kk] + lane*8 is contiguous 1KB.

// ---- prepack: 1 thread per (row, 8-float half-chunk); 8 threads/row ----
__global__ __launch_bounds__(256) void prepack_kernel(
    const float* __restrict__ L, const float* __restrict__ R,
    short* __restrict__ Apk, short* __restrict__ Bpk,
    float* __restrict__ lsq, float* __restrict__ rsq)
{
    const int t = blockIdx.x * 256 + threadIdx.x;   // 0..131071
    const int r = t >> 3;                           // 0..16383
    const int j = t & 7;                            // half-chunk
    const int kk = j >> 1, kh = j & 1;
    const bool isL = (r < NR);
    const int rr = isL ? r : r - NR;

    const float* src = (isL ? L : R) + (size_t)rr * D + j * 8;
    short* pk = isL ? Apk : Bpk;

    f32x4 v0 = *reinterpret_cast<const f32x4*>(src + 0);
    f32x4 v1 = *reinterpret_cast<const f32x4*>(src + 4);

    float p = 0.f;
    #pragma unroll
    for (int e = 0; e < 4; ++e) { p = fmaf(v0[e], v0[e], p); p = fmaf(v1[e], v1[e], p); }

    short8 w;
    #pragma unroll
    for (int e = 0; e < 4; ++e) { w[e] = f2bf(v0[e]); w[4+e] = f2bf(v1[e]); }
    *reinterpret_cast<short8*>(
        pk + ((size_t)(rr >> 5) * 4 + kk) * 512 + (kh * 32 + (rr & 31)) * 8) = w;

    p += __shfl_xor(p, 1, 64);
    p += __shfl_xor(p, 2, 64);
    p += __shfl_xor(p, 4, 64);
    if (j == 0) (isL ? lsq : rsq)[rr] = p;
}

// ---- main: 4 waves (2m x 2n), block 128m x 64n per iter, 8 n-iters ----
// grid (16, 64) = 1024 blocks; block covers 128 rows x 512 cols.
__global__ __launch_bounds__(256, 3) void pairdist_mfma_kernel(
    const short* __restrict__ Apk, const short* __restrict__ Bpk,
    const float* __restrict__ lsq, const float* __restrict__ rsq,
    float* __restrict__ slots)
{
    __shared__ float lsq_s[128];
    __shared__ __align__(16) float rsq_s[512];
    __shared__ float wmax_s[4];

    const int tid  = threadIdx.x;
    const int lane = tid & 63;
    const int wave = tid >> 6;
    const int wm = wave >> 1;      // 64-row half of 128
    const int wn = wave & 1;       // 32-col half of 64 per iter
    const int yb = blockIdx.x;     // 0..15 -> 512-col chunk of R
    const int xc = blockIdx.y;     // 0..63 -> 128-row chunk of L

    if (tid < 128) lsq_s[tid] = lsq[xc * 128 + tid];
    rsq_s[tid]       = rsq[yb * 512 + tid];
    rsq_s[256 + tid] = rsq[yb * 512 + 256 + tid];

    // A-frags, loop-invariant: row groups xc*4 + wm*2 + {0,1}, all K.
    short8 af[2][4];
    #pragma unroll
    for (int mi = 0; mi < 2; ++mi)
        #pragma unroll
        for (int kk = 0; kk < 4; ++kk)
            af[mi][kk] = *reinterpret_cast<const short8*>(
                Apk + ((size_t)(xc * 4 + wm * 2 + mi) * 4 + kk) * 512 + lane * 8);

    __syncthreads();   // norms staged (only barrier before reduce)

    const int col = lane & 31;
    const int h   = lane >> 5;

    // Deferred-lsq slot max: sm[mi][r] = max_t ( rq_t - 2*dot ). lsq added once.
    f32x16 sm[2];
    #pragma unroll
    for (int r = 0; r < 16; ++r) { sm[0][r] = -3.0e38f; sm[1][r] = -3.0e38f; }

    // B ping-pong buffers; prefetch iter 0.
    short8 bf[2][4];
    #pragma unroll
    for (int kk = 0; kk < 4; ++kk)
        bf[0][kk] = *reinterpret_cast<const short8*>(
            Bpk + ((size_t)(yb * 16 + wn) * 4 + kk) * 512 + lane * 8);

    #pragma unroll
    for (int t = 0; t < 8; ++t) {
        const int cur = t & 1;     // compile-time after full unroll
        if (t < 7) {               // prefetch next iter's B-frags
            const int cgB = yb * 16 + (t + 1) * 2 + wn;
            #pragma unroll
            for (int kk = 0; kk < 4; ++kk)
                bf[cur ^ 1][kk] = *reinterpret_cast<const short8*>(
                    Bpk + ((size_t)cgB * 4 + kk) * 512 + lane * 8);
        }

        f32x16 acc[2] = {};
        #pragma unroll
        for (int kk = 0; kk < 4; ++kk) {
            acc[0] = __builtin_amdgcn_mfma_f32_32x32x16_bf16(af[0][kk], bf[cur][kk], acc[0], 0, 0, 0);
            acc[1] = __builtin_amdgcn_mfma_f32_32x32x16_bf16(af[1][kk], bf[cur][kk], acc[1], 0, 0, 0);
        }

        const float rq = rsq_s[t * 64 + wn * 32 + col];
        #pragma unroll
        for (int r = 0; r < 16; ++r) {
            sm[0][r] = fmaxf(sm[0][r], fmaf(-2.f, acc[0][r], rq));
            sm[1][r] = fmaxf(sm[1][r], fmaf(-2.f, acc[1][r], rq));
        }
    }

    // Final: add per-row lsq (constant per slot), balanced tree max.
    // C layout (32x32): col = lane&31, row = (r&3) + 8*(r>>2) + 4*h
    float lmax = 0.f;
    #pragma unroll
    for (int mi = 0; mi < 2; ++mi) {
        const int rbase = wm * 64 + mi * 32 + 4 * h;
        f32x4 lq0 = *reinterpret_cast<const f32x4*>(&lsq_s[rbase +  0]);
        f32x4 lq1 = *reinterpret_cast<const f32x4*>(&lsq_s[rbase +  8]);
        f32x4 lq2 = *reinterpret_cast<const f32x4*>(&lsq_s[rbase + 16]);
        f32x4 lq3 = *reinterpret_cast<const f32x4*>(&lsq_s[rbase + 24]);
        float c[16];
        #pragma unroll
        for (int e = 0; e < 4; ++e) {
            c[0  + e] = lq0[e] + sm[mi][0  + e];
            c[4  + e] = lq1[e] + sm[mi][4  + e];
            c[8  + e] = lq2[e] + sm[mi][8  + e];
            c[12 + e] = lq3[e] + sm[mi][12 + e];
        }
        float y0 = fmaxf(c[0],  c[1]),  y1 = fmaxf(c[2],  c[3]);
        float y2 = fmaxf(c[4],  c[5]),  y3 = fmaxf(c[6],  c[7]);
        float y4 = fmaxf(c[8],  c[9]),  y5 = fmaxf(c[10], c[11]);
        float y6 = fmaxf(c[12], c[13]), y7 = fmaxf(c[14], c[15]);
        float z0 = fmaxf(y0, y1), z1 = fmaxf(y2, y3);
        float z2 = fmaxf(y4, y5), z3 = fmaxf(y6, y7);
        lmax = fmaxf(lmax, fmaxf(fmaxf(z0, z1), fmaxf(z2, z3)));
    }
    lmax = fmaxf(lmax, 0.f);

    #pragma unroll
    for (int off = 32; off >= 1; off >>= 1)
        lmax = fmaxf(lmax, __shfl_xor(lmax, off, 64));
    if (lane == 0) wmax_s[wave] = lmax;
    __syncthreads();
    if (tid == 0) {
        float bmax = fmaxf(fmaxf(wmax_s[0], wmax_s[1]), fmaxf(wmax_s[2], wmax_s[3]));
        slots[blockIdx.y * 16 + blockIdx.x] = bmax;
    }
}

// ---- finalize: reduce 1024 slots, sqrt, write scalar ----
__global__ __launch_bounds__(512) void finalize_kernel(
    const float* __restrict__ slots, float* __restrict__ out)
{
    __shared__ float wred[8];
    const int tid = threadIdx.x;
    float v = fmaxf(slots[tid], slots[tid + 512]);
    #pragma unroll
    for (int off = 32; off >= 1; off >>= 1)
        v = fmaxf(v, __shfl_xor(v, off, 64));
    if ((tid & 63) == 0) wred[tid >> 6] = v;
    __syncthreads();
    if (tid == 0) {
        float m = wred[0];
        #pragma unroll
        for (int i = 1; i < 8; ++i) m = fmaxf(m, wred[i]);
        out[0] = sqrtf(m);
    }
}

extern "C" void kernel_launch(void* const* d_in, const int* in_sizes, int n_in,
                              void* d_out, int out_size, void* d_ws, size_t ws_size,
                              hipStream_t stream) {
    const float* L = (const float*)d_in[0];
    const float* R = (const float*)d_in[1];

    short* Apk = (short*)d_ws;
    short* Bpk = Apk + (size_t)NR * D;           // 524288 shorts each
    float* lsqg = (float*)(Bpk + (size_t)NR * D);
    float* rsqg = lsqg + NR;
    float* slots = rsqg + NR;

    prepack_kernel<<<(2 * NR * 8) / 256, 256, 0, stream>>>(L, R, Apk, Bpk, lsqg, rsqg);
    pairdist_mfma_kernel<<<dim3(16, 64), dim3(256), 0, stream>>>(Apk, Bpk, lsqg, rsqg, slots);
    finalize_kernel<<<1, 512, 0, stream>>>(slots, (float*)d_out);
}